// Round 13
// baseline (123.705 us; speedup 1.0000x reference)
//
#include <hip/hip_runtime.h>

// Self-attention (SAGAN-style): B=8, C=64, H=W=64 -> N=4096, E=C/8=8.
// Round 13: the hidden ~36us was qkv, not the harness. Budget audit across
// r1-r12: total - attn(measured) = ~83us every round, but the visible
// harness poison fill is only ~42us (256MiB d_ws) + ~5us small fills ->
// ~36us unaccounted = qkv. Its per-thread pattern (64 x-loads at 16KB
// stride, x3 redundant proj passes, 1.5 waves/SIMD) is a latency-bound
// stride walk. Rebuild: single pass, LDS transpose --
//   stage x[b][:][n0:n0+256] (64KB, stride-260 pad) via coalesced float4;
//   each thread reads its pixel's 64-ch column from LDS (lanes ->
//   consecutive banks, conflict-free) and computes all 24 projections
//   (1536 FMA, W through the scalar pipe). Expected ~2-4us.
// Attn reverted to exact r11 (111.1us config): r12's 64-key groups were
// neutral-negative -> dropped. One variable this round.
// Kept (verified r6-r11): 2 q-tiles/wave, panelized V [b][128][16][32] with
// ones-row 8 (l = sum(p) via GEMM2), in-register P via permuted key map,
// unmasked quad-independent K loads, V row-clamp, raw v_exp, v_perm pack,
// depth-2 prefetch, fused Wo/residual epilogue.

#define BB   8
#define CC   64
#define NPIX 4096
#define EE   8
#define BN   (BB*NPIX)        // 32768
#define YSZ  (BB*CC*NPIX)     // 2097152
#define LOG2E 1.4426950408889634f

typedef __attribute__((ext_vector_type(8))) short bf16x8;
typedef __attribute__((ext_vector_type(4))) float f32x4;

__device__ __forceinline__ unsigned short f2bf_rne(float x) {
    unsigned u = __float_as_uint(x);
    u += 0x7FFFu + ((u >> 16) & 1u);
    return (unsigned short)(u >> 16);
}
// dst = [hi16(a), hi16(b)] in one v_perm_b32 (truncation; bias cancels in
// the softmax normalize since l sums the same truncated p via the ones-row).
__device__ __forceinline__ unsigned pack_bf_trunc(float a, float b) {
    return __builtin_amdgcn_perm(__float_as_uint(b), __float_as_uint(a),
                                 0x07060302u);
}

// ---- K1: QKV projection, single pass, LDS transpose ----
// Block = 256 pixels of one batch image; 128 blocks.
#define XS_STRIDE 260   // 256 + pad4: float4-aligned, conflict-free columns
__global__ __launch_bounds__(256) void qkv_kernel(
    const float* __restrict__ x,
    const float* __restrict__ Wk, const float* __restrict__ bk,
    const float* __restrict__ Wq, const float* __restrict__ bq,
    const float* __restrict__ Wv, const float* __restrict__ bv,
    unsigned short* __restrict__ QT, unsigned short* __restrict__ KT,
    unsigned short* __restrict__ VT)
{
    __shared__ float xs[CC*XS_STRIDE];   // 66.6 KB
    const int tid = threadIdx.x;
    const int bm  = blockIdx.x*256 + tid;
    const int b   = bm >> 12;
    const int n0  = (blockIdx.x & 15) * 256;

    // Stage: 64 c-rows x 256 n, coalesced float4 (16 iters/thread).
    const float* xb = x + (size_t)b*CC*NPIX + n0;
    #pragma unroll
    for (int j = tid; j < CC*64; j += 256) {
        const int c  = j >> 6;
        const int n4 = (j & 63) << 2;
        float4 v = *(const float4*)(xb + (size_t)c*NPIX + n4);
        *(float4*)(xs + c*XS_STRIDE + n4) = v;
    }
    __syncthreads();

    // Each thread: one pixel's 64-ch column -> 24 projections.
    float f[24];
    #pragma unroll
    for (int e = 0; e < EE; ++e) {
        f[e]    = bk[e];
        f[8+e]  = bq[e];
        f[16+e] = bv[e];
    }
    #pragma unroll 8
    for (int c = 0; c < CC; ++c) {
        float xc = xs[c*XS_STRIDE + tid];          // lanes -> consecutive banks
        #pragma unroll
        for (int e = 0; e < EE; ++e) {
            f[e]    = fmaf(Wk[e*CC+c], xc, f[e]);  // W uniform -> scalar pipe
            f[8+e]  = fmaf(Wq[e*CC+c], xc, f[8+e]);
            f[16+e] = fmaf(Wv[e*CC+c], xc, f[16+e]);
        }
    }

    const int n = bm & (NPIX-1);
    union { unsigned short s[8]; uint4 v; } kt, qt;
    #pragma unroll
    for (int e = 0; e < EE; ++e) {
        kt.s[e] = f2bf_rne(f[e]);
        qt.s[e] = f2bf_rne(f[8+e] * LOG2E);
    }
    *(uint4*)(KT + (size_t)bm*EE) = kt.v;
    *(uint4*)(QT + (size_t)bm*EE) = qt.v;

    // V panel write (layout verified r9-r12): panel p = n>>5, key c5 = n&31,
    // quad q(c5) block of 8: [0..3]=keys 4q..4q+3, [4..7]=keys 16+4q..+3.
    const int p   = n >> 5;
    const int c5  = n & 31;
    const int off = ((c5 & 15) >> 2)*8 + ((c5 >> 4) << 2) + (c5 & 3);
    unsigned short* vp = VT + ((size_t)(b*128 + p)*16)*32 + off;
    #pragma unroll
    for (int e = 0; e < EE; ++e) vp[e*32] = f2bf_rne(f[16+e]);
    vp[8*32] = 0x3F80;                             // ones row -> l via GEMM2
}

// ---- K2: flash attention, 2 q-tiles/wave + fused epilogue (exact r11) ----
// Block = 32 queries; 4 waves split the 4096 keys x4. Grid = 8*128 = 1024.
__global__ __launch_bounds__(256, 4) void attn_fused(
    const unsigned short* __restrict__ QT, const unsigned short* __restrict__ KT,
    const unsigned short* __restrict__ VT,
    const float* __restrict__ x, const float* __restrict__ Wo,
    const float* __restrict__ bo, const float* __restrict__ gamma,
    float* __restrict__ out)
{
    __shared__ float OB[3*2*256];  // waves 1..3 x {A,B} x 64 lanes x f32x4
    __shared__ float VL[32*12];    // normalized v per pixel
    __shared__ float Wos[CC*9];    // stride 9: conflict-free epilogue reads
    __shared__ float bos[CC];

    const int tid  = threadIdx.x;
    const int wave = tid >> 6, lane = tid & 63;
    const int quad = lane >> 4, lm = lane & 15;
    const int b  = blockIdx.x >> 7;
    const int m0 = (blockIdx.x & 127) * 32;

    for (int i = tid; i < CC*EE; i += 256) Wos[(i>>3)*9 + (i&7)] = Wo[i];
    if (tid < CC) bos[tid] = bo[tid];

    // B1 operands: only quad0 lanes carry real q rows; others stay zero.
    bf16x8 qfA = {0,0,0,0,0,0,0,0}, qfB = {0,0,0,0,0,0,0,0};
    if (quad == 0) {
        qfA = *(const bf16x8*)(QT + (size_t)(b*NPIX + m0 + lm)*EE);
        qfB = *(const bf16x8*)(QT + (size_t)(b*NPIX + m0 + 16 + lm)*EE);
    }

    f32x4 oaccA = {0.f,0.f,0.f,0.f}, oaccB = {0.f,0.f,0.f,0.f};
    const f32x4 zc = {0.f,0.f,0.f,0.f};

    const unsigned short* Kb = KT + (size_t)b*NPIX*EE;
    const int n_start = wave*1024;                 // split-K: 1024 keys/wave
    // K address is quad-independent: all quads hit the same 256B segment;
    // quads 1..3 hold real K x qf zero rows = 0 contribution.
    const unsigned short* kl = Kb + (size_t)(n_start + lm)*EE;
    // V panel: row clamp (rows 9..15 -> 8; same lines, C rows 9..15 discarded)
    const int lmv = (lm < 9) ? lm : 8;
    const unsigned short* vl = VT + ((size_t)(b*128 + (n_start >> 5))*16 + lmv)*32
                                  + quad*8;

    // 2-deep register pipeline
    bf16x8 kf0a = *(const bf16x8*)(kl);
    bf16x8 kf1a = *(const bf16x8*)(kl + 16*EE);
    bf16x8 vfa  = *(const bf16x8*)(vl);
    bf16x8 kf0b = *(const bf16x8*)(kl + 32*EE);
    bf16x8 kf1b = *(const bf16x8*)(kl + 48*EE);
    bf16x8 vfb  = *(const bf16x8*)(vl + 512);
    kl += 64*EE; vl += 1024;

    #pragma unroll 2
    for (int ch = 0; ch < 32; ++ch) {
        bf16x8 kf0 = kf0a, kf1 = kf1a, vf = vfa;
        kf0a = kf0b; kf1a = kf1b; vfa = vfb;       // ping-pong, no movs
        if (ch < 30) {                             // prefetch chunk ch+2
            kf0b = *(const bf16x8*)(kl);
            kf1b = *(const bf16x8*)(kl + 16*EE);
            vfb  = *(const bf16x8*)(vl);
            kl += 32*EE; vl += 512;
        }

        // S: C-layout lane (quad,lm) reg r = S[key][query];
        // s0: key = 4*quad + r; s1: key = 16 + 4*quad + r.
        f32x4 s0a = __builtin_amdgcn_mfma_f32_16x16x32_bf16(kf0, qfA, zc, 0, 0, 0);
        f32x4 s1a = __builtin_amdgcn_mfma_f32_16x16x32_bf16(kf1, qfA, zc, 0, 0, 0);
        f32x4 s0b = __builtin_amdgcn_mfma_f32_16x16x32_bf16(kf0, qfB, zc, 0, 0, 0);
        f32x4 s1b = __builtin_amdgcn_mfma_f32_16x16x32_bf16(kf1, qfB, zc, 0, 0, 0);

        float a0 = __builtin_amdgcn_exp2f(s0a.x), a1 = __builtin_amdgcn_exp2f(s0a.y);
        float a2 = __builtin_amdgcn_exp2f(s0a.z), a3 = __builtin_amdgcn_exp2f(s0a.w);
        float a4 = __builtin_amdgcn_exp2f(s1a.x), a5 = __builtin_amdgcn_exp2f(s1a.y);
        float a6 = __builtin_amdgcn_exp2f(s1a.z), a7 = __builtin_amdgcn_exp2f(s1a.w);
        float b0 = __builtin_amdgcn_exp2f(s0b.x), b1 = __builtin_amdgcn_exp2f(s0b.y);
        float b2 = __builtin_amdgcn_exp2f(s0b.z), b3 = __builtin_amdgcn_exp2f(s0b.w);
        float b4 = __builtin_amdgcn_exp2f(s1b.x), b5 = __builtin_amdgcn_exp2f(s1b.y);
        float b6 = __builtin_amdgcn_exp2f(s1b.z), b7 = __builtin_amdgcn_exp2f(s1b.w);

        // B2 fragment IS the C-layout regs under the permuted key map
        // (slot k=quad*8+j -> key quad*4+j (j<4) / 16+quad*4+(j-4)),
        // matching the V panel row layout. Verified r6-r12.
        union { unsigned u[4]; bf16x8 v; } puA, puB;
        puA.u[0] = pack_bf_trunc(a0, a1); puA.u[1] = pack_bf_trunc(a2, a3);
        puA.u[2] = pack_bf_trunc(a4, a5); puA.u[3] = pack_bf_trunc(a6, a7);
        puB.u[0] = pack_bf_trunc(b0, b1); puB.u[1] = pack_bf_trunc(b2, b3);
        puB.u[2] = pack_bf_trunc(b4, b5); puB.u[3] = pack_bf_trunc(b6, b7);
        oaccA = __builtin_amdgcn_mfma_f32_16x16x32_bf16(vf, puA.v, oaccA, 0, 0, 0);
        oaccB = __builtin_amdgcn_mfma_f32_16x16x32_bf16(vf, puB.v, oaccB, 0, 0, 0);
    }

    // cross-wave combine; l rides along in C-row 8 (quad2 lanes, reg .x)
    if (wave != 0) {
        *(f32x4*)(OB + ((size_t)(wave-1)*2 + 0)*256 + lane*4) = oaccA;
        *(f32x4*)(OB + ((size_t)(wave-1)*2 + 1)*256 + lane*4) = oaccB;
    }
    __syncthreads();
    if (wave == 0) {
        f32x4 oA = oaccA, oB = oaccB;
        #pragma unroll
        for (int w = 0; w < 3; ++w) {
            oA += *(f32x4*)(OB + ((size_t)w*2 + 0)*256 + lane*4);
            oB += *(f32x4*)(OB + ((size_t)w*2 + 1)*256 + lane*4);
        }
        float lA = __shfl(oA.x, 32 + lm);          // row 8 = sum of trunc(p)
        float lB = __shfl(oB.x, 32 + lm);
        float invA = 1.f / lA, invB = 1.f / lB;
        if (quad < 2) {                            // rows e = quad*4+reg in 0..7
            f32x4 sA = { oA.x*invA, oA.y*invA, oA.z*invA, oA.w*invA };
            f32x4 sB = { oB.x*invB, oB.y*invB, oB.z*invB, oB.w*invB };
            *(f32x4*)(VL + lm*12 + quad*4)        = sA;
            *(f32x4*)(VL + (16 + lm)*12 + quad*4) = sB;
        }
    }
    __syncthreads();

    // Fused epilogue: 32 px x 64 ch over 256 threads (8 ch each).
    const float g  = gamma[0];
    const int   px = tid & 31;
    const int   cg = tid >> 5;                     // 0..7
    const size_t base = (size_t)b*CC*NPIX + (m0 + px);
    float v[EE];
    #pragma unroll
    for (int e = 0; e < EE; ++e) v[e] = VL[px*12 + e];
    #pragma unroll
    for (int i = 0; i < 8; ++i) {
        const int c = cg*8 + i;
        float o = bos[c];
        #pragma unroll
        for (int e = 0; e < EE; ++e) o += Wos[c*9 + e] * v[e];
        out[(size_t)YSZ + base + (size_t)c*NPIX] = o;
        out[base + (size_t)c*NPIX] = g*o + x[base + (size_t)c*NPIX];
    }
    if (blockIdx.x == 0 && tid == 0) out[2*(size_t)YSZ] = g;  // gamma passthrough
}

extern "C" void kernel_launch(void* const* d_in, const int* in_sizes, int n_in,
                              void* d_out, int out_size, void* d_ws, size_t ws_size,
                              hipStream_t stream) {
    const float* x     = (const float*)d_in[0];
    const float* Wk    = (const float*)d_in[1];
    const float* bk    = (const float*)d_in[2];
    const float* Wq    = (const float*)d_in[3];
    const float* bq    = (const float*)d_in[4];
    const float* Wv    = (const float*)d_in[5];
    const float* bv    = (const float*)d_in[6];
    const float* Wo    = (const float*)d_in[7];
    const float* bo    = (const float*)d_in[8];
    const float* gamma = (const float*)d_in[9];
    float* out = (float*)d_out;

    // ws: QT(512KB) | KT(512KB) | VT(1MB bf16, panelized [b][128][16][32];
    // row 8 = ones, rows 9..15 poison -> only discarded C rows) = 2MB
    unsigned short* QT = (unsigned short*)d_ws;
    unsigned short* KT = QT + (size_t)BN*EE;
    unsigned short* VT = KT + (size_t)BN*EE;

    qkv_kernel<<<BN/256, 256, 0, stream>>>(x, Wk, bk, Wq, bq, Wv, bv, QT, KT, VT);
    attn_fused<<<BB*128, 256, 0, stream>>>(QT, KT, VT, x, Wo, bo, gamma, out);
}